// Round 2
// baseline (192.611 us; speedup 1.0000x reference)
//
#include <hip/hip_runtime.h>

// Depthwise 3x3 conv, stride 1, pad 1.
// x: (N=16, C=384, H=128, W=128) fp32, k: (C,1,3,3) fp32, out: same shape as x.
// Memory-bound: ~806 MB ideal traffic -> roofline ~128 us at 6.3 TB/s.
//
// R2: one block per (n,c) plane; each thread owns an 8-wide x 8-tall tile
// (two float4 per row), rolling 3-row x 10-float register window.
// Halves memory-instruction overhead vs R1's 4-wide tiles.

#define CC 384
#define HH 128
#define WW 128
#define NN 16

__global__ __launch_bounds__(256) void dwconv3x3(const float* __restrict__ x,
                                                 const float* __restrict__ k,
                                                 float* __restrict__ out) {
    const int nc = blockIdx.x;               // n*C + c
    const int c  = nc % CC;

    const int tid = (int)threadIdx.x;
    const int w0  = (tid & 15) << 3;         // 0,8,...,120
    const int h0  = (tid >> 4) << 3;         // 0,8,...,120

    const float* xp = x   + (size_t)nc * (HH * WW);
    float*       op = out + (size_t)nc * (HH * WW);

    // c is wave-uniform -> scalar weight loads.
    const float* kp = k + c * 9;
    const float w00 = kp[0], w01 = kp[1], w02 = kp[2];
    const float w10 = kp[3], w11 = kp[4], w12 = kp[5];
    const float w20 = kp[6], w21 = kp[7], w22 = kp[8];

    // r[.][0] = x[h][w0-1], r[.][1..8] = x[h][w0..w0+7], r[.][9] = x[h][w0+8]
    float r[3][10];

    auto load_row = [&](int h, float* rr) {
        if (h < 0 || h >= HH) {
            #pragma unroll
            for (int t = 0; t < 10; ++t) rr[t] = 0.f;
            return;
        }
        const float* p = xp + h * WW + w0;
        const float4 a = *reinterpret_cast<const float4*>(p);
        const float4 b = *reinterpret_cast<const float4*>(p + 4);
        rr[1] = a.x; rr[2] = a.y; rr[3] = a.z; rr[4] = a.w;
        rr[5] = b.x; rr[6] = b.y; rr[7] = b.z; rr[8] = b.w;
        rr[0] = (w0 > 0)      ? p[-1] : 0.f;   // halo: L1 hit (neighbor's row)
        rr[9] = (w0 + 8 < WW) ? p[8]  : 0.f;
    };

    load_row(h0 - 1, r[0]);
    load_row(h0,     r[1]);

    #pragma unroll
    for (int i = 0; i < 8; ++i) {
        const int h = h0 + i;
        float* ra = r[i % 3];        // row h-1
        float* rb = r[(i + 1) % 3];  // row h
        float* rc = r[(i + 2) % 3];  // row h+1
        load_row(h + 1, rc);

        float o[8];
        #pragma unroll
        for (int j = 0; j < 8; ++j) {
            o[j] = ra[j] * w00 + ra[j + 1] * w01 + ra[j + 2] * w02
                 + rb[j] * w10 + rb[j + 1] * w11 + rb[j + 2] * w12
                 + rc[j] * w20 + rc[j + 1] * w21 + rc[j + 2] * w22;
        }

        float* po = op + h * WW + w0;
        *reinterpret_cast<float4*>(po)     = make_float4(o[0], o[1], o[2], o[3]);
        *reinterpret_cast<float4*>(po + 4) = make_float4(o[4], o[5], o[6], o[7]);
    }
}

extern "C" void kernel_launch(void* const* d_in, const int* in_sizes, int n_in,
                              void* d_out, int out_size, void* d_ws, size_t ws_size,
                              hipStream_t stream) {
    const float* x = (const float*)d_in[0];
    const float* k = (const float*)d_in[1];
    float*     out = (float*)d_out;

    const int blocks = NN * CC;  // 6144 planes, one block each
    dwconv3x3<<<blocks, 256, 0, stream>>>(x, k, out);
}

// Round 3
// 171.911 us; speedup vs baseline: 1.1204x; 1.1204x over previous
//
#include <hip/hip_runtime.h>

// Depthwise 3x3 conv, stride 1, pad 1.
// x: (N=16, C=384, H=128, W=128) fp32, k: (C,1,3,3) fp32, out: same shape as x.
// Memory-bound: ~806 MB ideal traffic -> roofline ~128 us at 6.29 TB/s copy BW.
//
// R3: R1's layout (thread = 4-wide float4 x 8-tall strip, wave = 32 contiguous
// lanes covering a full 128-float row) but burst-loads all 10 input rows into
// registers up front (deep MLP, like a copy kernel), then computes/stores the
// 8 output rows. All array indices compile-time constant -> pure registers.

#define CC 384
#define HH 128
#define WW 128
#define NN 16

__global__ __launch_bounds__(256) void dwconv3x3(const float* __restrict__ x,
                                                 const float* __restrict__ k,
                                                 float* __restrict__ out) {
    const int b    = blockIdx.x;
    const int half = b & 1;
    const int nc   = b >> 1;                 // n*C + c
    const int c    = nc % CC;

    const int strip = half * 256 + (int)threadIdx.x;  // 0..511
    const int w0 = (strip & 31) << 2;                 // 0,4,...,124
    const int h0 = (strip >> 5) << 3;                 // 0,8,...,120

    const float* xp = x   + (size_t)nc * (HH * WW);
    float*       op = out + (size_t)nc * (HH * WW);

    // c is wave-uniform -> weights land in SGPRs.
    const float* kp = k + c * 9;
    const float w00 = kp[0], w01 = kp[1], w02 = kp[2];
    const float w10 = kp[3], w11 = kp[4], w12 = kp[5];
    const float w20 = kp[6], w21 = kp[7], w22 = kp[8];

    // r[t][0] = x[h][w0-1], r[t][1..4] = x[h][w0..w0+3], r[t][5] = x[h][w0+4]
    // for h = h0-1+t, t = 0..9.  Burst-issued: 10 independent float4 loads.
    float r[10][6];

    #pragma unroll
    for (int t = 0; t < 10; ++t) {
        const int h = h0 - 1 + t;
        if (h < 0 || h >= HH) {
            #pragma unroll
            for (int j = 0; j < 6; ++j) r[t][j] = 0.f;
        } else {
            const float* p = xp + h * WW + w0;
            const float4 m = *reinterpret_cast<const float4*>(p);
            r[t][1] = m.x; r[t][2] = m.y; r[t][3] = m.z; r[t][4] = m.w;
            r[t][0] = (w0 > 0)      ? p[-1] : 0.f;  // same-line L1 hit
            r[t][5] = (w0 + 4 < WW) ? p[4]  : 0.f;
        }
    }

    #pragma unroll
    for (int i = 0; i < 8; ++i) {
        float o[4];
        #pragma unroll
        for (int j = 0; j < 4; ++j) {
            o[j] = r[i][j]     * w00 + r[i][j + 1]     * w01 + r[i][j + 2]     * w02
                 + r[i + 1][j] * w10 + r[i + 1][j + 1] * w11 + r[i + 1][j + 2] * w12
                 + r[i + 2][j] * w20 + r[i + 2][j + 1] * w21 + r[i + 2][j + 2] * w22;
        }
        *reinterpret_cast<float4*>(op + (h0 + i) * WW + w0) =
            make_float4(o[0], o[1], o[2], o[3]);
    }
}

extern "C" void kernel_launch(void* const* d_in, const int* in_sizes, int n_in,
                              void* d_out, int out_size, void* d_ws, size_t ws_size,
                              hipStream_t stream) {
    const float* x = (const float*)d_in[0];
    const float* k = (const float*)d_in[1];
    float*     out = (float*)d_out;

    const int blocks = NN * CC * 2;  // 12288
    dwconv3x3<<<blocks, 256, 0, stream>>>(x, k, out);
}

// Round 4
// 163.971 us; speedup vs baseline: 1.1747x; 1.0484x over previous
//
#include <hip/hip_runtime.h>

// Depthwise 3x3 conv, stride 1, pad 1.
// x: (N=16, C=384, H=128, W=128) fp32, k: (C,1,3,3) fp32, out: same shape as x.
// Memory-bound: ~806 MB ideal traffic -> roofline ~128 us at 6.29 TB/s copy BW.
//
// R4: R1 structure (rolling 3-row window, low VGPR) with two deltas:
//  - halo elements come from __shfl of the neighboring lane's float4 instead
//    of 2 extra scalar global loads per row (3x fewer load instructions);
//  - 16-tall strips, one block per plane (vertical halo re-read 25% -> 12.5%).

#define CC 384
#define HH 128
#define WW 128
#define NN 16

__global__ __launch_bounds__(256) void dwconv3x3(const float* __restrict__ x,
                                                 const float* __restrict__ k,
                                                 float* __restrict__ out) {
    const int nc = blockIdx.x;               // n*C + c
    const int c  = nc % CC;

    const int tid   = (int)threadIdx.x;
    const int w_idx = tid & 31;              // 32 lanes span one 128-float row
    const int w0    = w_idx << 2;            // 0,4,...,124
    const int h0    = (tid >> 5) << 4;       // 0,16,...,112 (16-tall strips)

    const float* xp = x   + (size_t)nc * (HH * WW);
    float*       op = out + (size_t)nc * (HH * WW);

    // c is block-uniform -> weights in SGPRs.
    const float* kp = k + c * 9;
    const float w00 = kp[0], w01 = kp[1], w02 = kp[2];
    const float w10 = kp[3], w11 = kp[4], w12 = kp[5];
    const float w20 = kp[6], w21 = kp[7], w22 = kp[8];

    const bool lEdge = (w_idx == 0);         // true W-boundary (also lane 32)
    const bool rEdge = (w_idx == 31);        // true W-boundary (also lane 31/63)

    // r[t][0] = x[h][w0-1], r[t][1..4] = x[h][w0..w0+3], r[t][5] = x[h][w0+4]
    float r[3][6];

    // Load one input row; halos via cross-lane shuffle of the float4.
    // Lane boundaries 31<->32 coincide with W edges, so the mask is exact.
#define LOAD_ROW(h, ri)                                                        \
    {                                                                          \
        float4 m = make_float4(0.f, 0.f, 0.f, 0.f);                            \
        if ((unsigned)(h) < (unsigned)HH)                                      \
            m = *reinterpret_cast<const float4*>(xp + (h) * WW + w0);          \
        r[ri][1] = m.x; r[ri][2] = m.y; r[ri][3] = m.z; r[ri][4] = m.w;        \
        const float lv = __shfl_up(m.w, 1);                                    \
        const float rv = __shfl_down(m.x, 1);                                  \
        r[ri][0] = lEdge ? 0.f : lv;                                           \
        r[ri][5] = rEdge ? 0.f : rv;                                           \
    }

    LOAD_ROW(h0 - 1, 0)
    LOAD_ROW(h0,     1)

    #pragma unroll
    for (int i = 0; i < 16; ++i) {
        const int h = h0 + i;
        LOAD_ROW(h + 1, (i + 2) % 3)

        float o[4];
        #pragma unroll
        for (int j = 0; j < 4; ++j) {
            o[j] = r[i % 3][j]           * w00 + r[i % 3][j + 1]       * w01
                 + r[i % 3][j + 2]       * w02
                 + r[(i + 1) % 3][j]     * w10 + r[(i + 1) % 3][j + 1] * w11
                 + r[(i + 1) % 3][j + 2] * w12
                 + r[(i + 2) % 3][j]     * w20 + r[(i + 2) % 3][j + 1] * w21
                 + r[(i + 2) % 3][j + 2] * w22;
        }
        *reinterpret_cast<float4*>(op + h * WW + w0) =
            make_float4(o[0], o[1], o[2], o[3]);
    }
#undef LOAD_ROW
}

extern "C" void kernel_launch(void* const* d_in, const int* in_sizes, int n_in,
                              void* d_out, int out_size, void* d_ws, size_t ws_size,
                              hipStream_t stream) {
    const float* x = (const float*)d_in[0];
    const float* k = (const float*)d_in[1];
    float*     out = (float*)d_out;

    const int blocks = NN * CC;  // one 256-thread block per (n,c) plane
    dwconv3x3<<<blocks, 256, 0, stream>>>(x, k, out);
}

// Round 5
// 152.142 us; speedup vs baseline: 1.2660x; 1.0778x over previous
//
#include <hip/hip_runtime.h>

// Depthwise 3x3 conv, stride 1, pad 1.
// x: (N=16, C=384, H=128, W=128) fp32, k: (C,1,3,3) fp32, out: same shape as x.
// Memory-bound: ideal 403 MB read + 403 MB write -> ~128 us at 6.29 TB/s.
//
// R5: bound HBM fetch structurally. Block = half plane (64 output rows).
// Stage 66 input rows (33 KB) into LDS once (coalesced float4 burst, rows
// read exactly 1.03x), one barrier, then each thread computes a 4-wide x
// 8-tall strip from LDS. 4 blocks/CU (132 KB LDS), 16 waves/CU.

#define CC 384
#define HH 128
#define WW 128
#define NN 16

__global__ __launch_bounds__(256) void dwconv3x3(const float* __restrict__ x,
                                                 const float* __restrict__ k,
                                                 float* __restrict__ out) {
    __shared__ float lds[66][WW];   // rows hbase-1 .. hbase+64

    const int b     = blockIdx.x;
    const int half  = b & 1;
    const int nc    = b >> 1;        // n*C + c
    const int c     = nc % CC;
    const int hbase = half * 64;

    const float* xp = x   + (size_t)nc * (HH * WW);
    float*       op = out + (size_t)nc * (HH * WW);

    const int tid = (int)threadIdx.x;

    // ---- Stage: 66 rows * 32 float4-slots = 2112 slots, burst of 8-9/thread.
    #pragma unroll
    for (int it = 0; it < 9; ++it) {
        const int s = tid + it * 256;
        if (s < 66 * 32) {
            const int row = s >> 5;          // 0..65
            const int col = (s & 31) << 2;   // 0,4,...,124
            const int h   = hbase - 1 + row;
            float4 m = make_float4(0.f, 0.f, 0.f, 0.f);
            if ((unsigned)h < (unsigned)HH)
                m = *reinterpret_cast<const float4*>(xp + h * WW + col);
            *reinterpret_cast<float4*>(&lds[row][col]) = m;
        }
    }

    // Weights: c is block-uniform -> scalar loads (overlaps with staging).
    const float* kp = k + c * 9;
    const float w00 = kp[0], w01 = kp[1], w02 = kp[2];
    const float w10 = kp[3], w11 = kp[4], w12 = kp[5];
    const float w20 = kp[6], w21 = kp[7], w22 = kp[8];

    __syncthreads();

    // ---- Compute: thread = 4-wide x 8-tall strip, rolling 3-row LDS window.
    const int w0   = (tid & 31) << 2;        // 0,4,...,124
    const int hloc = (tid >> 5) << 3;        // 0,8,...,56 (local output row)

    // r[t][0] = row[w0-1], r[t][1..4] = row[w0..w0+3], r[t][5] = row[w0+4]
    float r[3][6];

#define LDSROW(ri, rr)                                                         \
    {                                                                          \
        const float* p = &lds[(rr)][0];                                        \
        const float4 m = *reinterpret_cast<const float4*>(p + w0);             \
        r[ri][1] = m.x; r[ri][2] = m.y; r[ri][3] = m.z; r[ri][4] = m.w;        \
        r[ri][0] = (w0 > 0)      ? p[w0 - 1] : 0.f;                            \
        r[ri][5] = (w0 + 4 < WW) ? p[w0 + 4] : 0.f;                            \
    }

    LDSROW(0, hloc)          // staged row hloc   == global row hbase+hloc-1
    LDSROW(1, hloc + 1)

    #pragma unroll
    for (int i = 0; i < 8; ++i) {
        LDSROW((i + 2) % 3, hloc + i + 2)

        float o[4];
        #pragma unroll
        for (int j = 0; j < 4; ++j) {
            o[j] = r[i % 3][j]           * w00 + r[i % 3][j + 1]       * w01
                 + r[i % 3][j + 2]       * w02
                 + r[(i + 1) % 3][j]     * w10 + r[(i + 1) % 3][j + 1] * w11
                 + r[(i + 1) % 3][j + 2] * w12
                 + r[(i + 2) % 3][j]     * w20 + r[(i + 2) % 3][j + 1] * w21
                 + r[(i + 2) % 3][j + 2] * w22;
        }
        *reinterpret_cast<float4*>(op + (hbase + hloc + i) * WW + w0) =
            make_float4(o[0], o[1], o[2], o[3]);
    }
#undef LDSROW
}

extern "C" void kernel_launch(void* const* d_in, const int* in_sizes, int n_in,
                              void* d_out, int out_size, void* d_ws, size_t ws_size,
                              hipStream_t stream) {
    const float* x = (const float*)d_in[0];
    const float* k = (const float*)d_in[1];
    float*     out = (float*)d_out;

    const int blocks = NN * CC * 2;  // one block per half plane
    dwconv3x3<<<blocks, 256, 0, stream>>>(x, k, out);
}

// Round 7
// 149.636 us; speedup vs baseline: 1.2872x; 1.0167x over previous
//
#include <hip/hip_runtime.h>

// Depthwise 3x3 conv, stride 1, pad 1.
// x: (N=16, C=384, H=128, W=128) fp32, k: (C,1,3,3) fp32, out: same shape as x.
// Memory-bound: ideal 403 MB read + 403 MB write -> ~128 us at 6.29 TB/s.
//
// R7 = R5 (full LDS staging, fetch bounded at 1.03x) + nontemporal output
// stores via a native ext_vector float4 (HIP's float4 class is rejected by
// __builtin_nontemporal_store). Output is write-once, never re-read ->
// bypass L2 write-allocation churn.

#define CC 384
#define HH 128
#define WW 128
#define NN 16

typedef float vfloat4 __attribute__((ext_vector_type(4)));

__global__ __launch_bounds__(256) void dwconv3x3(const float* __restrict__ x,
                                                 const float* __restrict__ k,
                                                 float* __restrict__ out) {
    __shared__ float lds[66][WW];   // rows hbase-1 .. hbase+64

    const int b     = blockIdx.x;
    const int half  = b & 1;
    const int nc    = b >> 1;        // n*C + c
    const int c     = nc % CC;
    const int hbase = half * 64;

    const float* xp = x   + (size_t)nc * (HH * WW);
    float*       op = out + (size_t)nc * (HH * WW);

    const int tid = (int)threadIdx.x;

    // ---- Stage: 66 rows * 32 float4-slots = 2112 slots, burst of 8-9/thread.
    #pragma unroll
    for (int it = 0; it < 9; ++it) {
        const int s = tid + it * 256;
        if (s < 66 * 32) {
            const int row = s >> 5;          // 0..65
            const int col = (s & 31) << 2;   // 0,4,...,124
            const int h   = hbase - 1 + row;
            float4 m = make_float4(0.f, 0.f, 0.f, 0.f);
            if ((unsigned)h < (unsigned)HH)
                m = *reinterpret_cast<const float4*>(xp + h * WW + col);
            *reinterpret_cast<float4*>(&lds[row][col]) = m;
        }
    }

    // Weights: c is block-uniform -> scalar loads (overlap with staging).
    const float* kp = k + c * 9;
    const float w00 = kp[0], w01 = kp[1], w02 = kp[2];
    const float w10 = kp[3], w11 = kp[4], w12 = kp[5];
    const float w20 = kp[6], w21 = kp[7], w22 = kp[8];

    __syncthreads();

    // ---- Compute: thread = 4-wide x 8-tall strip, rolling 3-row LDS window.
    const int w0   = (tid & 31) << 2;        // 0,4,...,124
    const int hloc = (tid >> 5) << 3;        // 0,8,...,56 (local output row)

    float r[3][6];

#define LDSROW(ri, rr)                                                         \
    {                                                                          \
        const float* p = &lds[(rr)][0];                                        \
        const float4 m = *reinterpret_cast<const float4*>(p + w0);             \
        r[ri][1] = m.x; r[ri][2] = m.y; r[ri][3] = m.z; r[ri][4] = m.w;        \
        r[ri][0] = (w0 > 0)      ? p[w0 - 1] : 0.f;                            \
        r[ri][5] = (w0 + 4 < WW) ? p[w0 + 4] : 0.f;                            \
    }

    LDSROW(0, hloc)          // staged row hloc == global row hbase+hloc-1
    LDSROW(1, hloc + 1)

    #pragma unroll
    for (int i = 0; i < 8; ++i) {
        LDSROW((i + 2) % 3, hloc + i + 2)

        float o[4];
        #pragma unroll
        for (int j = 0; j < 4; ++j) {
            o[j] = r[i % 3][j]           * w00 + r[i % 3][j + 1]       * w01
                 + r[i % 3][j + 2]       * w02
                 + r[(i + 1) % 3][j]     * w10 + r[(i + 1) % 3][j + 1] * w11
                 + r[(i + 1) % 3][j + 2] * w12
                 + r[(i + 2) % 3][j]     * w20 + r[(i + 2) % 3][j + 1] * w21
                 + r[(i + 2) % 3][j + 2] * w22;
        }
        vfloat4 ov;
        ov.x = o[0]; ov.y = o[1]; ov.z = o[2]; ov.w = o[3];
        // Nontemporal: output is write-once, never re-read -> skip L2 alloc.
        __builtin_nontemporal_store(
            ov, reinterpret_cast<vfloat4*>(op + (hbase + hloc + i) * WW + w0));
    }
#undef LDSROW
}

extern "C" void kernel_launch(void* const* d_in, const int* in_sizes, int n_in,
                              void* d_out, int out_size, void* d_ws, size_t ws_size,
                              hipStream_t stream) {
    const float* x = (const float*)d_in[0];
    const float* k = (const float*)d_in[1];
    float*     out = (float*)d_out;

    const int blocks = NN * CC * 2;  // one block per half plane
    dwconv3x3<<<blocks, 256, 0, stream>>>(x, k, out);
}

// Round 8
// 147.614 us; speedup vs baseline: 1.3048x; 1.0137x over previous
//
#include <hip/hip_runtime.h>

// Depthwise 3x3 conv, stride 1, pad 1.
// x: (N=16, C=384, H=128, W=128) fp32, k: (C,1,3,3) fp32, out: same shape as x.
// Memory-bound: ideal 403 MB read + 403 MB write -> ~128 us at 6.29 TB/s.
//
// R8 = R7 (LDS staging + NT stores) with:
//  - 32-row blocks (17.4 KB LDS) -> 8 blocks/CU (was 4): finer read/write
//    stream interleave, 2x wave-level MLP;
//  - bijective XCD-chunked blockIdx swizzle: blocks sharing halo rows land
//    on the same XCD's L2 (consecutive logical ids, ~same dispatch time),
//    so the 6% halo re-read becomes L2 hits instead of HBM refetch.

#define CC 384
#define HH 128
#define WW 128
#define NN 16
#define ROWS 32                  // output rows per block
#define NWG (NN * CC * 4)        // 24576, divisible by 8

typedef float vfloat4 __attribute__((ext_vector_type(4)));

__global__ __launch_bounds__(256) void dwconv3x3(const float* __restrict__ x,
                                                 const float* __restrict__ k,
                                                 float* __restrict__ out) {
    __shared__ float lds[ROWS + 2][WW];   // rows hbase-1 .. hbase+ROWS

    // XCD-chunked swizzle: hardware d -> logical L; consecutive L share an XCD.
    const int d = (int)blockIdx.x;
    const int L = (d & 7) * (NWG / 8) + (d >> 3);

    const int quarter = L & 3;
    const int nc      = L >> 2;          // n*C + c
    const int c       = nc % CC;
    const int hbase   = quarter * ROWS;

    const float* xp = x   + (size_t)nc * (HH * WW);
    float*       op = out + (size_t)nc * (HH * WW);

    const int tid = (int)threadIdx.x;

    // ---- Stage: 34 rows * 32 float4-slots = 1088 slots, 5 bursts/thread.
    #pragma unroll
    for (int it = 0; it < 5; ++it) {
        const int s = tid + it * 256;
        if (s < (ROWS + 2) * 32) {
            const int row = s >> 5;          // 0..33
            const int col = (s & 31) << 2;   // 0,4,...,124
            const int h   = hbase - 1 + row;
            float4 m = make_float4(0.f, 0.f, 0.f, 0.f);
            if ((unsigned)h < (unsigned)HH)
                m = *reinterpret_cast<const float4*>(xp + h * WW + col);
            *reinterpret_cast<float4*>(&lds[row][col]) = m;
        }
    }

    // Weights: c is block-uniform -> scalar loads (overlap with staging).
    const float* kp = k + c * 9;
    const float w00 = kp[0], w01 = kp[1], w02 = kp[2];
    const float w10 = kp[3], w11 = kp[4], w12 = kp[5];
    const float w20 = kp[6], w21 = kp[7], w22 = kp[8];

    __syncthreads();

    // ---- Compute: thread = 4-wide x 4-tall strip, rolling 3-row LDS window.
    const int w0   = (tid & 31) << 2;        // 0,4,...,124
    const int hloc = (tid >> 5) << 2;        // 0,4,...,28 (local output row)

    float r[3][6];

#define LDSROW(ri, rr)                                                         \
    {                                                                          \
        const float* p = &lds[(rr)][0];                                        \
        const float4 m = *reinterpret_cast<const float4*>(p + w0);             \
        r[ri][1] = m.x; r[ri][2] = m.y; r[ri][3] = m.z; r[ri][4] = m.w;        \
        r[ri][0] = (w0 > 0)      ? p[w0 - 1] : 0.f;                            \
        r[ri][5] = (w0 + 4 < WW) ? p[w0 + 4] : 0.f;                            \
    }

    LDSROW(0, hloc)          // staged row hloc == global row hbase+hloc-1
    LDSROW(1, hloc + 1)

    #pragma unroll
    for (int i = 0; i < 4; ++i) {
        LDSROW((i + 2) % 3, hloc + i + 2)

        float o[4];
        #pragma unroll
        for (int j = 0; j < 4; ++j) {
            o[j] = r[i % 3][j]           * w00 + r[i % 3][j + 1]       * w01
                 + r[i % 3][j + 2]       * w02
                 + r[(i + 1) % 3][j]     * w10 + r[(i + 1) % 3][j + 1] * w11
                 + r[(i + 1) % 3][j + 2] * w12
                 + r[(i + 2) % 3][j]     * w20 + r[(i + 2) % 3][j + 1] * w21
                 + r[(i + 2) % 3][j + 2] * w22;
        }
        vfloat4 ov;
        ov.x = o[0]; ov.y = o[1]; ov.z = o[2]; ov.w = o[3];
        __builtin_nontemporal_store(
            ov, reinterpret_cast<vfloat4*>(op + (hbase + hloc + i) * WW + w0));
    }
#undef LDSROW
}

extern "C" void kernel_launch(void* const* d_in, const int* in_sizes, int n_in,
                              void* d_out, int out_size, void* d_ws, size_t ws_size,
                              hipStream_t stream) {
    const float* x = (const float*)d_in[0];
    const float* k = (const float*)d_in[1];
    float*     out = (float*)d_out;

    dwconv3x3<<<NWG, 256, 0, stream>>>(x, k, out);
}

// Round 10
// 147.012 us; speedup vs baseline: 1.3102x; 1.0041x over previous
//
#include <hip/hip_runtime.h>

// Depthwise 3x3 conv, stride 1, pad 1.
// x: (N=16, C=384, H=128, W=128) fp32, k: (C,1,3,3) fp32, out: same shape as x.
// Memory-bound: ideal 403 MB read + 403 MB write -> ~128 us at 6.29 TB/s.
//
// R10 = R9 with the global_load_lds mask bug fixed: the intrinsic writes at
// wave-uniform-base + lane*16, so ALL lanes must stay active (lane-masking
// shifts the implied base when lane 0 is off -> R9's corruption). OOB halo
// rows now load a clamped in-bounds address and are zero-overwritten via
// ds_write between two barriers.

#define CC 384
#define HH 128
#define WW 128
#define NN 16
#define ROWS 32                  // output rows per block
#define NWG (NN * CC * 4)        // 24576, divisible by 8

typedef float vfloat4 __attribute__((ext_vector_type(4)));

__global__ __launch_bounds__(256) void dwconv3x3(const float* __restrict__ x,
                                                 const float* __restrict__ k,
                                                 float* __restrict__ out) {
    __shared__ float lds[ROWS + 2][WW];   // rows hbase-1 .. hbase+ROWS

    // XCD-chunked swizzle: hardware d -> logical L; consecutive L share an XCD.
    const int d = (int)blockIdx.x;
    const int L = (d & 7) * (NWG / 8) + (d >> 3);

    const int quarter = L & 3;
    const int nc      = L >> 2;          // n*C + c
    const int c       = nc % CC;
    const int hbase   = quarter * ROWS;

    const float* xp = x   + (size_t)nc * (HH * WW);
    float*       op = out + (size_t)nc * (HH * WW);

    const int tid = (int)threadIdx.x;

    // ---- Stage: 34 rows * 32 float4-slots = 1088 slots, direct global->LDS.
    // slot s -> LDS byte s*16 (linear in lane). NO lane masking: OOB rows
    // load a clamped valid address and are zeroed after the barrier.
    #pragma unroll
    for (int it = 0; it < 5; ++it) {
        const int s = tid + it * 256;
        if (s < (ROWS + 2) * 32) {       // uniform per wave (1088 = 17 waves)
            const int row = s >> 5;          // 0..33
            const int col = (s & 31) << 2;   // 0,4,...,124
            int h = hbase - 1 + row;
            h = (h < 0) ? 0 : ((h >= HH) ? HH - 1 : h);   // clamp, keep lane on
            const __attribute__((address_space(1))) float* gsrc =
                (const __attribute__((address_space(1))) float*)(xp + h * WW + col);
            __attribute__((address_space(3))) float* ldst =
                (__attribute__((address_space(3))) float*)(&lds[row][col]);
            __builtin_amdgcn_global_load_lds(gsrc, ldst, 16, 0, 0);
        }
    }

    // Weights: c is block-uniform -> scalar loads (overlap with staging).
    const float* kp = k + c * 9;
    const float w00 = kp[0], w01 = kp[1], w02 = kp[2];
    const float w10 = kp[3], w11 = kp[4], w12 = kp[5];
    const float w20 = kp[6], w21 = kp[7], w22 = kp[8];

    __syncthreads();   // drains vmcnt -> all DMA writes landed

    // Zero-overwrite the out-of-plane halo rows (loaded garbage above).
    if (hbase == 0 && tid < 32)
        *reinterpret_cast<float4*>(&lds[0][tid << 2]) =
            make_float4(0.f, 0.f, 0.f, 0.f);
    if (hbase + ROWS == HH && tid < 32)
        *reinterpret_cast<float4*>(&lds[ROWS + 1][tid << 2]) =
            make_float4(0.f, 0.f, 0.f, 0.f);
    __syncthreads();

    // ---- Compute: thread = 4-wide x 4-tall strip, rolling 3-row LDS window.
    const int w0   = (tid & 31) << 2;        // 0,4,...,124
    const int hloc = (tid >> 5) << 2;        // 0,4,...,28 (local output row)

    float r[3][6];

#define LDSROW(ri, rr)                                                         \
    {                                                                          \
        const float* p = &lds[(rr)][0];                                        \
        const float4 m = *reinterpret_cast<const float4*>(p + w0);             \
        r[ri][1] = m.x; r[ri][2] = m.y; r[ri][3] = m.z; r[ri][4] = m.w;        \
        r[ri][0] = (w0 > 0)      ? p[w0 - 1] : 0.f;                            \
        r[ri][5] = (w0 + 4 < WW) ? p[w0 + 4] : 0.f;                            \
    }

    LDSROW(0, hloc)          // staged row hloc == global row hbase+hloc-1
    LDSROW(1, hloc + 1)

    #pragma unroll
    for (int i = 0; i < 4; ++i) {
        LDSROW((i + 2) % 3, hloc + i + 2)

        float o[4];
        #pragma unroll
        for (int j = 0; j < 4; ++j) {
            o[j] = r[i % 3][j]           * w00 + r[i % 3][j + 1]       * w01
                 + r[i % 3][j + 2]       * w02
                 + r[(i + 1) % 3][j]     * w10 + r[(i + 1) % 3][j + 1] * w11
                 + r[(i + 1) % 3][j + 2] * w12
                 + r[(i + 2) % 3][j]     * w20 + r[(i + 2) % 3][j + 1] * w21
                 + r[(i + 2) % 3][j + 2] * w22;
        }
        vfloat4 ov;
        ov.x = o[0]; ov.y = o[1]; ov.z = o[2]; ov.w = o[3];
        __builtin_nontemporal_store(
            ov, reinterpret_cast<vfloat4*>(op + (hbase + hloc + i) * WW + w0));
    }
#undef LDSROW
}

extern "C" void kernel_launch(void* const* d_in, const int* in_sizes, int n_in,
                              void* d_out, int out_size, void* d_ws, size_t ws_size,
                              hipStream_t stream) {
    const float* x = (const float*)d_in[0];
    const float* k = (const float*)d_in[1];
    float*     out = (float*)d_out;

    dwconv3x3<<<NWG, 256, 0, stream>>>(x, k, out);
}